// Round 1
// baseline (458.827 us; speedup 1.0000x reference)
//
#include <hip/hip_runtime.h>
#include <math.h>

// Problem constants (from reference): B=512, T=4096, C=7, H=3
constexpr long long N_ROWS = 512LL * 4096LL;   // 2,097,152
constexpr int ROWS_PER_THREAD = 4;             // makes all loads 16B-aligned float4/int4
constexpr int BLOCK = 256;

// d_ws layout: [0]=float loss_sum, [1]=uint n_correct, [2]=uint n_valid

__global__ __launch_bounds__(BLOCK) void shortloss_main(
    const float* __restrict__ out0,
    const float* __restrict__ out1,
    const float* __restrict__ out2,
    const int*   __restrict__ labels,   // [N,3] int32
    const float* __restrict__ mask,     // [N]
    const float* __restrict__ reward,   // [N,3]
    float*        __restrict__ ws_loss,
    unsigned int* __restrict__ ws_corr,
    unsigned int* __restrict__ ws_valid)
{
    const long long t    = (long long)blockIdx.x * BLOCK + threadIdx.x;
    const long long row0 = t * ROWS_PER_THREAD;

    // ---- mask: 4 rows, one float4 (row0 % 4 == 0 -> 16B aligned) ----
    float4 m4 = *reinterpret_cast<const float4*>(mask + row0);
    const float mm[4] = {m4.x, m4.y, m4.z, m4.w};
    bool valid[4];
    int  vcount = 0;
    #pragma unroll
    for (int r = 0; r < 4; ++r) { valid[r] = mm[r] < 0.5f; vcount += valid[r] ? 1 : 0; }

    // ---- labels: 12 contiguous ints = 3 x int4 (48B aligned) ----
    int lab[12];
    {
        const int4* lp = reinterpret_cast<const int4*>(labels + row0 * 3);
        int4 a = lp[0], b = lp[1], c = lp[2];
        lab[0]=a.x; lab[1]=a.y; lab[2]=a.z;  lab[3]=a.w;
        lab[4]=b.x; lab[5]=b.y; lab[6]=b.z;  lab[7]=b.w;
        lab[8]=c.x; lab[9]=c.y; lab[10]=c.z; lab[11]=c.w;
    }

    // ---- reward: 12 contiguous floats = 3 x float4 ----
    float rw[12];
    {
        const float4* rp = reinterpret_cast<const float4*>(reward + row0 * 3);
        float4 a = rp[0], b = rp[1], c = rp[2];
        rw[0]=a.x; rw[1]=a.y; rw[2]=a.z;  rw[3]=a.w;
        rw[4]=b.x; rw[5]=b.y; rw[6]=b.z;  rw[7]=b.w;
        rw[8]=c.x; rw[9]=c.y; rw[10]=c.z; rw[11]=c.w;
    }

    float loss_local = 0.0f;
    bool  corr[4] = {true, true, true, true};

    const float* outs[3] = {out0, out1, out2};
    #pragma unroll
    for (int h = 0; h < 3; ++h) {
        // 4 rows x 7 classes = 28 contiguous floats = 7 x float4 (112B aligned)
        const float4* op4 = reinterpret_cast<const float4*>(outs[h] + row0 * 7);
        float v[28];
        #pragma unroll
        for (int i = 0; i < 7; ++i) {
            float4 q = op4[i];
            v[4*i+0]=q.x; v[4*i+1]=q.y; v[4*i+2]=q.z; v[4*i+3]=q.w;
        }
        #pragma unroll
        for (int r = 0; r < 4; ++r) {
            const int lbl = lab[r*3 + h];
            // argmax with first-max tie-break (strict >) — matches jnp.argmax
            float best  = v[r*7];
            int   bestc = 0;
            #pragma unroll
            for (int c = 1; c < 7; ++c) {
                float val = v[r*7 + c];
                if (val > best) { best = val; bestc = c; }
            }
            // gather op = v[r*7 + lbl] via select chain (no dynamic reg index)
            float opv = v[r*7];
            #pragma unroll
            for (int c = 1; c < 7; ++c) {
                opv = (lbl == c) ? v[r*7 + c] : opv;
            }
            loss_local += valid[r] ? __logf(opv) * rw[r*3 + h] : 0.0f;
            corr[r] = corr[r] && (bestc == lbl);
        }
    }

    int ccount = 0;
    #pragma unroll
    for (int r = 0; r < 4; ++r) ccount += (corr[r] && valid[r]) ? 1 : 0;

    // ---- wave-64 reduction, then one atomic per wave ----
    #pragma unroll
    for (int off = 32; off > 0; off >>= 1) {
        loss_local += __shfl_down(loss_local, off, 64);
        ccount     += __shfl_down(ccount,     off, 64);
        vcount     += __shfl_down(vcount,     off, 64);
    }
    if ((threadIdx.x & 63) == 0) {
        atomicAdd(ws_loss,  loss_local);
        atomicAdd(ws_corr,  (unsigned int)ccount);
        atomicAdd(ws_valid, (unsigned int)vcount);
    }
}

__global__ void shortloss_final(const float* __restrict__ ws_loss,
                                const unsigned int* __restrict__ ws_corr,
                                const unsigned int* __restrict__ ws_valid,
                                float* __restrict__ out)
{
    float nv = (float)(*ws_valid);
    out[0] = -(*ws_loss) / nv;
    out[1] = (float)(*ws_corr);
    out[2] = nv;
}

extern "C" void kernel_launch(void* const* d_in, const int* in_sizes, int n_in,
                              void* d_out, int out_size, void* d_ws, size_t ws_size,
                              hipStream_t stream) {
    const float* out0   = (const float*)d_in[0];
    const float* out1   = (const float*)d_in[1];
    const float* out2   = (const float*)d_in[2];
    const int*   labels = (const int*)  d_in[3];
    const float* mask   = (const float*)d_in[4];
    const float* reward = (const float*)d_in[5];

    float*        ws_loss  = (float*)d_ws;
    unsigned int* ws_corr  = (unsigned int*)d_ws + 1;
    unsigned int* ws_valid = (unsigned int*)d_ws + 2;

    // zero the accumulators every call (ws is re-poisoned to 0xAA by harness)
    hipMemsetAsync(d_ws, 0, 16, stream);

    const long long n_threads = N_ROWS / ROWS_PER_THREAD;   // 524,288
    const int blocks = (int)(n_threads / BLOCK);            // 2048

    shortloss_main<<<blocks, BLOCK, 0, stream>>>(
        out0, out1, out2, labels, mask, reward, ws_loss, ws_corr, ws_valid);
    shortloss_final<<<1, 1, 0, stream>>>(ws_loss, ws_corr, ws_valid, (float*)d_out);
}

// Round 2
// 228.705 us; speedup vs baseline: 2.0062x; 2.0062x over previous
//
#include <hip/hip_runtime.h>

// Problem constants (from reference): B=512, T=4096, C=7, H=3
constexpr long long N_ROWS = 512LL * 4096LL;   // 2,097,152
constexpr int ROWS_PER_THREAD = 4;             // makes all loads 16B-aligned float4/int4
constexpr int BLOCK = 256;
constexpr int NBLOCKS = (int)(N_ROWS / (long long)ROWS_PER_THREAD / BLOCK);  // 2048

// d_ws layout: float4 partials[NBLOCKS]  (loss, n_correct, n_valid, pad) = 32 KB

__global__ __launch_bounds__(BLOCK) void shortloss_main(
    const float* __restrict__ out0,
    const float* __restrict__ out1,
    const float* __restrict__ out2,
    const int*   __restrict__ labels,   // [N,3] int32
    const float* __restrict__ mask,     // [N]
    const float* __restrict__ reward,   // [N,3]
    float4*      __restrict__ partials) // [NBLOCKS]
{
    const long long t    = (long long)blockIdx.x * BLOCK + threadIdx.x;
    const long long row0 = t * ROWS_PER_THREAD;

    // ---- mask: 4 rows, one float4 (16B aligned) ----
    float4 m4 = *reinterpret_cast<const float4*>(mask + row0);
    const float mm[4] = {m4.x, m4.y, m4.z, m4.w};
    bool valid[4];
    int  vcount = 0;
    #pragma unroll
    for (int r = 0; r < 4; ++r) { valid[r] = mm[r] < 0.5f; vcount += valid[r] ? 1 : 0; }

    // ---- labels: 12 contiguous ints = 3 x int4 ----
    int lab[12];
    {
        const int4* lp = reinterpret_cast<const int4*>(labels + row0 * 3);
        int4 a = lp[0], b = lp[1], c = lp[2];
        lab[0]=a.x; lab[1]=a.y; lab[2]=a.z;  lab[3]=a.w;
        lab[4]=b.x; lab[5]=b.y; lab[6]=b.z;  lab[7]=b.w;
        lab[8]=c.x; lab[9]=c.y; lab[10]=c.z; lab[11]=c.w;
    }

    // ---- reward: 12 contiguous floats = 3 x float4 ----
    float rw[12];
    {
        const float4* rp = reinterpret_cast<const float4*>(reward + row0 * 3);
        float4 a = rp[0], b = rp[1], c = rp[2];
        rw[0]=a.x; rw[1]=a.y; rw[2]=a.z;  rw[3]=a.w;
        rw[4]=b.x; rw[5]=b.y; rw[6]=b.z;  rw[7]=b.w;
        rw[8]=c.x; rw[9]=c.y; rw[10]=c.z; rw[11]=c.w;
    }

    float loss_local = 0.0f;
    bool  corr[4] = {true, true, true, true};

    const float* outs[3] = {out0, out1, out2};
    #pragma unroll
    for (int h = 0; h < 3; ++h) {
        // 4 rows x 7 classes = 28 contiguous floats = 7 x float4
        const float4* op4 = reinterpret_cast<const float4*>(outs[h] + row0 * 7);
        float v[28];
        #pragma unroll
        for (int i = 0; i < 7; ++i) {
            float4 q = op4[i];
            v[4*i+0]=q.x; v[4*i+1]=q.y; v[4*i+2]=q.z; v[4*i+3]=q.w;
        }
        #pragma unroll
        for (int r = 0; r < 4; ++r) {
            const int lbl = lab[r*3 + h];
            // argmax with first-max tie-break (strict >) — matches jnp.argmax
            float best  = v[r*7];
            int   bestc = 0;
            #pragma unroll
            for (int c = 1; c < 7; ++c) {
                float val = v[r*7 + c];
                if (val > best) { best = val; bestc = c; }
            }
            // gather op = v[r*7 + lbl] via select chain (no dynamic reg index)
            float opv = v[r*7];
            #pragma unroll
            for (int c = 1; c < 7; ++c) {
                opv = (lbl == c) ? v[r*7 + c] : opv;
            }
            loss_local += valid[r] ? __logf(opv) * rw[r*3 + h] : 0.0f;
            corr[r] = corr[r] && (bestc == lbl);
        }
    }

    int ccount = 0;
    #pragma unroll
    for (int r = 0; r < 4; ++r) ccount += (corr[r] && valid[r]) ? 1 : 0;

    // ---- wave-64 shuffle reduction ----
    #pragma unroll
    for (int off = 32; off > 0; off >>= 1) {
        loss_local += __shfl_down(loss_local, off, 64);
        ccount     += __shfl_down(ccount,     off, 64);
        vcount     += __shfl_down(vcount,     off, 64);
    }

    // ---- cross-wave via LDS, one plain float4 store per block ----
    __shared__ float s_loss[BLOCK / 64];
    __shared__ int   s_c[BLOCK / 64];
    __shared__ int   s_v[BLOCK / 64];
    const int wave = threadIdx.x >> 6;
    if ((threadIdx.x & 63) == 0) {
        s_loss[wave] = loss_local;
        s_c[wave]    = ccount;
        s_v[wave]    = vcount;
    }
    __syncthreads();
    if (threadIdx.x == 0) {
        float L = 0.0f; int C = 0, V = 0;
        #pragma unroll
        for (int w = 0; w < BLOCK / 64; ++w) { L += s_loss[w]; C += s_c[w]; V += s_v[w]; }
        partials[blockIdx.x] = make_float4(L, (float)C, (float)V, 0.0f);
    }
}

__global__ __launch_bounds__(256) void shortloss_reduce(
    const float4* __restrict__ partials,
    float* __restrict__ out)
{
    float L = 0.0f, C = 0.0f, V = 0.0f;
    for (int i = threadIdx.x; i < NBLOCKS; i += 256) {
        float4 p = partials[i];
        L += p.x; C += p.y; V += p.z;
    }
    #pragma unroll
    for (int off = 32; off > 0; off >>= 1) {
        L += __shfl_down(L, off, 64);
        C += __shfl_down(C, off, 64);
        V += __shfl_down(V, off, 64);
    }
    __shared__ float sL[4], sC[4], sV[4];
    const int wave = threadIdx.x >> 6;
    if ((threadIdx.x & 63) == 0) { sL[wave] = L; sC[wave] = C; sV[wave] = V; }
    __syncthreads();
    if (threadIdx.x == 0) {
        float l = 0.0f, c = 0.0f, v = 0.0f;
        #pragma unroll
        for (int w = 0; w < 4; ++w) { l += sL[w]; c += sC[w]; v += sV[w]; }
        out[0] = -l / v;
        out[1] = c;
        out[2] = v;
    }
}

extern "C" void kernel_launch(void* const* d_in, const int* in_sizes, int n_in,
                              void* d_out, int out_size, void* d_ws, size_t ws_size,
                              hipStream_t stream) {
    const float* out0   = (const float*)d_in[0];
    const float* out1   = (const float*)d_in[1];
    const float* out2   = (const float*)d_in[2];
    const int*   labels = (const int*)  d_in[3];
    const float* mask   = (const float*)d_in[4];
    const float* reward = (const float*)d_in[5];

    float4* partials = (float4*)d_ws;   // 2048 * 16 B = 32 KB

    shortloss_main<<<NBLOCKS, BLOCK, 0, stream>>>(
        out0, out1, out2, labels, mask, reward, partials);
    shortloss_reduce<<<1, 256, 0, stream>>>(partials, (float*)d_out);
}

// Round 3
// 227.698 us; speedup vs baseline: 2.0151x; 1.0044x over previous
//
#include <hip/hip_runtime.h>

// Problem constants (from reference): B=512, T=4096, C=7, H=3
constexpr long long N_ROWS = 512LL * 4096LL;   // 2,097,152
constexpr int BLOCK  = 256;
constexpr int CHUNK  = 256;                    // rows staged per chunk
constexpr int NBLOCKS = 2048;
constexpr int NCHUNKS_TOTAL   = (int)(N_ROWS / CHUNK);        // 8192
constexpr int CHUNKS_PER_BLOCK = NCHUNKS_TOTAL / NBLOCKS;     // 4

// LDS layout (in 4-byte words):
//   lds_out : 3 heads * 256 rows * 7 floats = 5376
//   lds_lab : 256 * 3 ints                  =  768
//   lds_rw  : 256 * 3 floats                =  768
//   lds_msk : 256 floats                    =  256
//   total 7168 words = 28 KB -> 5 blocks/CU

__device__ __forceinline__ void async_copy16(const void* g, void* l) {
    __builtin_amdgcn_global_load_lds(
        (const __attribute__((address_space(1))) unsigned int*)g,
        (__attribute__((address_space(3))) unsigned int*)l,
        16, 0, 0);
}

__global__ __launch_bounds__(BLOCK) void shortloss_main(
    const float* __restrict__ out0,
    const float* __restrict__ out1,
    const float* __restrict__ out2,
    const int*   __restrict__ labels,   // [N,3] int32
    const float* __restrict__ mask,     // [N]
    const float* __restrict__ reward,   // [N,3]
    float4*      __restrict__ partials) // [NBLOCKS]
{
    __shared__ float lds[7168];
    float* lds_out = lds;                       // 3 * 1792 floats
    int*   lds_lab = (int*)(lds + 5376);        // 768 ints
    float* lds_rw  = lds + 6144;                // 768 floats
    float* lds_msk = lds + 6912;                // 256 floats

    const int tid = threadIdx.x;
    const float* outs[3] = {out0, out1, out2};

    float loss_local = 0.0f;
    int   ccount = 0, vcount = 0;

    for (int k = 0; k < CHUNKS_PER_BLOCK; ++k) {
        const long long c    = (long long)k * NBLOCKS + blockIdx.x;
        const long long row0 = c * CHUNK;

        // ---- stage chunk into LDS, all lane-contiguous 16B async copies ----
        // out heads: 448 float4 units each (256 full-wave + 192 on waves 0-2)
        #pragma unroll
        for (int h = 0; h < 3; ++h) {
            const float* src = outs[h] + row0 * 7;
            float*       dst = lds_out + h * 1792;
            async_copy16(src + (size_t)tid * 4, dst + tid * 4);
            if (tid < 192)
                async_copy16(src + (size_t)(256 + tid) * 4, dst + (256 + tid) * 4);
        }
        if (tid < 192) {  // waves 0-2 fully active
            async_copy16(labels + row0 * 3 + (size_t)tid * 4, lds_lab + tid * 4);
            async_copy16(reward + row0 * 3 + (size_t)tid * 4, lds_rw  + tid * 4);
        }
        if (tid < 64) {   // wave 0 fully active
            async_copy16(mask + row0 + (size_t)tid * 4, lds_msk + tid * 4);
        }
        __syncthreads();  // drains vmcnt (global_load_lds) before LDS reads

        // ---- compute: one row per thread ----
        const bool valid = lds_msk[tid] < 0.5f;
        vcount += valid ? 1 : 0;

        int lab[3], h_ok = 1;
        float rw[3];
        #pragma unroll
        for (int h = 0; h < 3; ++h) {
            lab[h] = lds_lab[tid * 3 + h];
            rw[h]  = lds_rw [tid * 3 + h];
        }

        float lsum = 0.0f;
        #pragma unroll
        for (int h = 0; h < 3; ++h) {
            const float* vr = lds_out + h * 1792 + tid * 7;
            float v[7];
            #pragma unroll
            for (int cc = 0; cc < 7; ++cc) v[cc] = vr[cc];

            // argmax, strict > (first-max tie-break, matches jnp.argmax)
            float best = v[0]; int bestc = 0;
            #pragma unroll
            for (int cc = 1; cc < 7; ++cc)
                if (v[cc] > best) { best = v[cc]; bestc = cc; }

            // gather true-class prob via select chain
            float opv = v[0];
            #pragma unroll
            for (int cc = 1; cc < 7; ++cc)
                opv = (lab[h] == cc) ? v[cc] : opv;

            lsum += __logf(opv) * rw[h];
            h_ok &= (bestc == lab[h]) ? 1 : 0;
        }
        loss_local += valid ? lsum : 0.0f;
        ccount     += (valid && h_ok) ? 1 : 0;

        __syncthreads();  // protect LDS before next chunk's staging
    }

    // ---- wave-64 shuffle reduction ----
    float L = loss_local;
    int   C = ccount, V = vcount;
    #pragma unroll
    for (int off = 32; off > 0; off >>= 1) {
        L += __shfl_down(L, off, 64);
        C += __shfl_down(C, off, 64);
        V += __shfl_down(V, off, 64);
    }

    __shared__ float sL[BLOCK / 64];
    __shared__ int   sC[BLOCK / 64], sV[BLOCK / 64];
    const int wave = tid >> 6;
    if ((tid & 63) == 0) { sL[wave] = L; sC[wave] = C; sV[wave] = V; }
    __syncthreads();
    if (tid == 0) {
        float l = 0.0f; int cc = 0, vv = 0;
        #pragma unroll
        for (int w = 0; w < BLOCK / 64; ++w) { l += sL[w]; cc += sC[w]; vv += sV[w]; }
        partials[blockIdx.x] = make_float4(l, (float)cc, (float)vv, 0.0f);
    }
}

__global__ __launch_bounds__(256) void shortloss_reduce(
    const float4* __restrict__ partials,
    float* __restrict__ out)
{
    float L = 0.0f, C = 0.0f, V = 0.0f;
    for (int i = threadIdx.x; i < NBLOCKS; i += 256) {
        float4 p = partials[i];
        L += p.x; C += p.y; V += p.z;
    }
    #pragma unroll
    for (int off = 32; off > 0; off >>= 1) {
        L += __shfl_down(L, off, 64);
        C += __shfl_down(C, off, 64);
        V += __shfl_down(V, off, 64);
    }
    __shared__ float sL[4], sC[4], sV[4];
    const int wave = threadIdx.x >> 6;
    if ((threadIdx.x & 63) == 0) { sL[wave] = L; sC[wave] = C; sV[wave] = V; }
    __syncthreads();
    if (threadIdx.x == 0) {
        float l = 0.0f, c = 0.0f, v = 0.0f;
        #pragma unroll
        for (int w = 0; w < 4; ++w) { l += sL[w]; c += sC[w]; v += sV[w]; }
        out[0] = -l / v;
        out[1] = c;
        out[2] = v;
    }
}

extern "C" void kernel_launch(void* const* d_in, const int* in_sizes, int n_in,
                              void* d_out, int out_size, void* d_ws, size_t ws_size,
                              hipStream_t stream) {
    const float* out0   = (const float*)d_in[0];
    const float* out1   = (const float*)d_in[1];
    const float* out2   = (const float*)d_in[2];
    const int*   labels = (const int*)  d_in[3];
    const float* mask   = (const float*)d_in[4];
    const float* reward = (const float*)d_in[5];

    float4* partials = (float4*)d_ws;   // 2048 * 16 B = 32 KB

    shortloss_main<<<NBLOCKS, BLOCK, 0, stream>>>(
        out0, out1, out2, labels, mask, reward, partials);
    shortloss_reduce<<<1, 256, 0, stream>>>(partials, (float*)d_out);
}

// Round 4
// 226.818 us; speedup vs baseline: 2.0229x; 1.0039x over previous
//
#include <hip/hip_runtime.h>

// Problem constants (from reference): B=512, T=4096, C=7, H=3
constexpr long long N_ROWS = 512LL * 4096LL;   // 2,097,152
constexpr int ROWS_PER_THREAD = 4;             // 16B-aligned float4/int4 everywhere
constexpr int BLOCK = 256;
constexpr int NBLOCKS = (int)(N_ROWS / (long long)ROWS_PER_THREAD / BLOCK);  // 2048

// d_ws layout: float4 partials[NBLOCKS] = 32 KB

// __launch_bounds__(256, 2): waves/EU floor = 2 -> VGPR cap 256. We WANT high
// register pressure here: all 28 float4 loads (112 VGPRs of payload) must be
// in flight simultaneously so each wave holds ~28KB outstanding. R2's
// VGPR_Count=32 meant the compiler serialized loads into ~4-load batches.
__global__ __launch_bounds__(BLOCK, 2) void shortloss_main(
    const float* __restrict__ out0,
    const float* __restrict__ out1,
    const float* __restrict__ out2,
    const int*   __restrict__ labels,   // [N,3] int32
    const float* __restrict__ mask,     // [N]
    const float* __restrict__ reward,   // [N,3]
    float4*      __restrict__ partials) // [NBLOCKS]
{
    const long long t    = (long long)blockIdx.x * BLOCK + threadIdx.x;
    const long long row0 = t * ROWS_PER_THREAD;

    // ================= HOISTED LOADS: all 28 independent, no use before all issued =================
    const float4* o0p = reinterpret_cast<const float4*>(out0 + row0 * 7);
    const float4* o1p = reinterpret_cast<const float4*>(out1 + row0 * 7);
    const float4* o2p = reinterpret_cast<const float4*>(out2 + row0 * 7);
    const int4*   lp  = reinterpret_cast<const int4*>(labels + row0 * 3);
    const float4* rp  = reinterpret_cast<const float4*>(reward + row0 * 3);

    float4 o[3][7];
    #pragma unroll
    for (int i = 0; i < 7; ++i) o[0][i] = o0p[i];
    #pragma unroll
    for (int i = 0; i < 7; ++i) o[1][i] = o1p[i];
    #pragma unroll
    for (int i = 0; i < 7; ++i) o[2][i] = o2p[i];
    int4   li0 = lp[0], li1 = lp[1], li2 = lp[2];
    float4 rf0 = rp[0], rf1 = rp[1], rf2 = rp[2];
    float4 m4  = *reinterpret_cast<const float4*>(mask + row0);

    // ================= COMPUTE =================
    const float mm[4] = {m4.x, m4.y, m4.z, m4.w};
    bool valid[4];
    int  vcount = 0;
    #pragma unroll
    for (int r = 0; r < 4; ++r) { valid[r] = mm[r] < 0.5f; vcount += valid[r] ? 1 : 0; }

    const int lab[12] = {li0.x, li0.y, li0.z, li0.w,
                         li1.x, li1.y, li1.z, li1.w,
                         li2.x, li2.y, li2.z, li2.w};
    const float rw[12] = {rf0.x, rf0.y, rf0.z, rf0.w,
                          rf1.x, rf1.y, rf1.z, rf1.w,
                          rf2.x, rf2.y, rf2.z, rf2.w};

    float loss_local = 0.0f;
    bool  corr[4] = {true, true, true, true};

    #pragma unroll
    for (int h = 0; h < 3; ++h) {
        float v[28];
        #pragma unroll
        for (int i = 0; i < 7; ++i) {
            v[4*i+0] = o[h][i].x; v[4*i+1] = o[h][i].y;
            v[4*i+2] = o[h][i].z; v[4*i+3] = o[h][i].w;
        }
        #pragma unroll
        for (int r = 0; r < 4; ++r) {
            const int lbl = lab[r*3 + h];
            // argmax, strict > (first-max tie-break, matches jnp.argmax)
            float best  = v[r*7];
            int   bestc = 0;
            #pragma unroll
            for (int c = 1; c < 7; ++c) {
                float val = v[r*7 + c];
                if (val > best) { best = val; bestc = c; }
            }
            // gather true-class prob via select chain (no dynamic reg index)
            float opv = v[r*7];
            #pragma unroll
            for (int c = 1; c < 7; ++c)
                opv = (lbl == c) ? v[r*7 + c] : opv;

            loss_local += valid[r] ? __logf(opv) * rw[r*3 + h] : 0.0f;
            corr[r] = corr[r] && (bestc == lbl);
        }
    }

    int ccount = 0;
    #pragma unroll
    for (int r = 0; r < 4; ++r) ccount += (corr[r] && valid[r]) ? 1 : 0;

    // ---- wave-64 shuffle reduction ----
    #pragma unroll
    for (int off = 32; off > 0; off >>= 1) {
        loss_local += __shfl_down(loss_local, off, 64);
        ccount     += __shfl_down(ccount,     off, 64);
        vcount     += __shfl_down(vcount,     off, 64);
    }

    __shared__ float sL[BLOCK / 64];
    __shared__ int   sC[BLOCK / 64], sV[BLOCK / 64];
    const int wave = threadIdx.x >> 6;
    if ((threadIdx.x & 63) == 0) { sL[wave] = loss_local; sC[wave] = ccount; sV[wave] = vcount; }
    __syncthreads();
    if (threadIdx.x == 0) {
        float l = 0.0f; int cc = 0, vv = 0;
        #pragma unroll
        for (int w = 0; w < BLOCK / 64; ++w) { l += sL[w]; cc += sC[w]; vv += sV[w]; }
        partials[blockIdx.x] = make_float4(l, (float)cc, (float)vv, 0.0f);
    }
}

__global__ __launch_bounds__(256) void shortloss_reduce(
    const float4* __restrict__ partials,
    float* __restrict__ out)
{
    float L = 0.0f, C = 0.0f, V = 0.0f;
    for (int i = threadIdx.x; i < NBLOCKS; i += 256) {
        float4 p = partials[i];
        L += p.x; C += p.y; V += p.z;
    }
    #pragma unroll
    for (int off = 32; off > 0; off >>= 1) {
        L += __shfl_down(L, off, 64);
        C += __shfl_down(C, off, 64);
        V += __shfl_down(V, off, 64);
    }
    __shared__ float sL[4], sC[4], sV[4];
    const int wave = threadIdx.x >> 6;
    if ((threadIdx.x & 63) == 0) { sL[wave] = L; sC[wave] = C; sV[wave] = V; }
    __syncthreads();
    if (threadIdx.x == 0) {
        float l = 0.0f, c = 0.0f, v = 0.0f;
        #pragma unroll
        for (int w = 0; w < 4; ++w) { l += sL[w]; c += sC[w]; v += sV[w]; }
        out[0] = -l / v;
        out[1] = c;
        out[2] = v;
    }
}

extern "C" void kernel_launch(void* const* d_in, const int* in_sizes, int n_in,
                              void* d_out, int out_size, void* d_ws, size_t ws_size,
                              hipStream_t stream) {
    const float* out0   = (const float*)d_in[0];
    const float* out1   = (const float*)d_in[1];
    const float* out2   = (const float*)d_in[2];
    const int*   labels = (const int*)  d_in[3];
    const float* mask   = (const float*)d_in[4];
    const float* reward = (const float*)d_in[5];

    float4* partials = (float4*)d_ws;   // 2048 * 16 B = 32 KB

    shortloss_main<<<NBLOCKS, BLOCK, 0, stream>>>(
        out0, out1, out2, labels, mask, reward, partials);
    shortloss_reduce<<<1, 256, 0, stream>>>(partials, (float*)d_out);
}

// Round 6
// 226.024 us; speedup vs baseline: 2.0300x; 1.0035x over previous
//
#include <hip/hip_runtime.h>

// Problem constants: B=512, T=4096, C=7, H=3 ; N = 2,097,152 rows
constexpr long long N_ROWS = 512LL * 4096LL;
constexpr int BLOCK   = 256;                 // 4 waves
constexpr int CHUNK   = 256;                 // rows per staged chunk
constexpr int CPB     = 4;                   // consecutive chunks per block
constexpr int NBLOCKS = (int)(N_ROWS / ((long long)CHUNK * CPB));  // 2048

// Per-buffer LDS layout (float words) — identical to R3's proven layout:
//   [0,5376)    out: 3 heads * 256 rows * 7
//   [5376,6144) labels: 256*3 int32
//   [6144,6912) reward: 256*3
//   [6912,7168) mask: 256
constexpr int BUF_WORDS = 7168;              // 28672 B; double = 57344 B -> 2 blocks/CU

__device__ __forceinline__ void async16(const float* g, float* l) {
    __builtin_amdgcn_global_load_lds(
        (const __attribute__((address_space(1))) unsigned int*)g,
        (__attribute__((address_space(3))) unsigned int*)l,
        16, 0, 0);
}

__global__ __launch_bounds__(BLOCK) void shortloss_main(
    const float* __restrict__ out0,
    const float* __restrict__ out1,
    const float* __restrict__ out2,
    const int*   __restrict__ labels,   // [N,3] int32
    const float* __restrict__ mask,     // [N]
    const float* __restrict__ reward,   // [N,3]
    float4*      __restrict__ partials) // [NBLOCKS]
{
    __shared__ float lds[2 * BUF_WORDS];
    const int tid = threadIdx.x;
    const long long c0 = (long long)blockIdx.x * CPB;   // consecutive chunks per block
    const float* outs[3] = {out0, out1, out2};

    // WHOLE-WAVE staging only (R5 lesson: partial exec masks break global_load_lds's
    // wave-uniform-base + lane*16 contract). tid<192 -> waves 0-2 fully active;
    // tid<64 -> wave 0 fully active. Identity lane->slot mapping throughout.
    auto stage = [&](long long c, int b) {
        float* buf = lds + b * BUF_WORDS;
        #pragma unroll
        for (int h = 0; h < 3; ++h) {
            const float* src = outs[h] + c * (CHUNK * 7);   // 1792 floats, 16B aligned
            float*       dst = buf + h * 1792;
            async16(src + 4 * (size_t)tid, dst + 4 * tid);                    // units 0..255
            if (tid < 192)
                async16(src + 4 * (size_t)(256 + tid), dst + 4 * (256 + tid)); // units 256..447
        }
        if (tid < 192) {
            async16((const float*)(labels) + c * (CHUNK * 3) + 4 * (size_t)tid, buf + 5376 + 4 * tid);
            async16(reward + c * (CHUNK * 3) + 4 * (size_t)tid,                 buf + 6144 + 4 * tid);
        }
        if (tid < 64)
            async16(mask + c * CHUNK + 4 * (size_t)tid, buf + 6912 + 4 * tid);
    };

    float L = 0.0f;
    int   C = 0, V = 0;

    auto compute = [&](int b) {
        const float* buf  = lds + b * BUF_WORDS;
        const int*   labp = (const int*)(buf + 5376);
        const bool valid = buf[6912 + tid] < 0.5f;
        V += valid ? 1 : 0;
        int   ok   = 1;
        float lsum = 0.0f;
        #pragma unroll
        for (int h = 0; h < 3; ++h) {
            const int lbl = labp[tid * 3 + h];
            const float* vr = buf + h * 1792 + tid * 7;   // odd stride -> conflict-free
            float v[7];
            #pragma unroll
            for (int cc = 0; cc < 7; ++cc) v[cc] = vr[cc];

            // argmax, strict > (first-max tie-break, matches jnp.argmax)
            float best = v[0]; int bestc = 0;
            #pragma unroll
            for (int cc = 1; cc < 7; ++cc)
                if (v[cc] > best) { best = v[cc]; bestc = cc; }

            // gather true-class prob via select chain (no dynamic reg index)
            float opv = v[0];
            #pragma unroll
            for (int cc = 1; cc < 7; ++cc)
                opv = (lbl == cc) ? v[cc] : opv;

            lsum += __logf(opv) * buf[6144 + tid * 3 + h];
            ok &= (bestc == lbl) ? 1 : 0;
        }
        L += valid ? lsum : 0.0f;
        C += (valid && ok) ? 1 : 0;
    };

    // Software pipeline: issue stage(k+1) BEFORE compute(k). The barrier's
    // vmcnt(0) drain then waits on loads issued a full compute-phase earlier,
    // and a fresh stage is issued immediately after each barrier release, so
    // the memory queue is never empty for long.
    stage(c0, 0);
    __syncthreads();
    #pragma unroll
    for (int k = 0; k < CPB; ++k) {
        if (k + 1 < CPB) stage(c0 + k + 1, (k + 1) & 1);
        compute(k & 1);
        __syncthreads();
    }

    // ---- block reduction ----
    #pragma unroll
    for (int off = 32; off > 0; off >>= 1) {
        L += __shfl_down(L, off, 64);
        C += __shfl_down(C, off, 64);
        V += __shfl_down(V, off, 64);
    }
    __shared__ float sL[BLOCK / 64];
    __shared__ int   sC[BLOCK / 64], sV[BLOCK / 64];
    const int wave = tid >> 6;
    if ((tid & 63) == 0) { sL[wave] = L; sC[wave] = C; sV[wave] = V; }
    __syncthreads();
    if (tid == 0) {
        float l = 0.0f; int cc = 0, vv = 0;
        #pragma unroll
        for (int w = 0; w < BLOCK / 64; ++w) { l += sL[w]; cc += sC[w]; vv += sV[w]; }
        partials[blockIdx.x] = make_float4(l, (float)cc, (float)vv, 0.0f);
    }
}

__global__ __launch_bounds__(256) void shortloss_reduce(
    const float4* __restrict__ partials,
    float* __restrict__ out)
{
    float L = 0.0f, C = 0.0f, V = 0.0f;
    for (int i = threadIdx.x; i < NBLOCKS; i += 256) {
        float4 p = partials[i];
        L += p.x; C += p.y; V += p.z;
    }
    #pragma unroll
    for (int off = 32; off > 0; off >>= 1) {
        L += __shfl_down(L, off, 64);
        C += __shfl_down(C, off, 64);
        V += __shfl_down(V, off, 64);
    }
    __shared__ float sL[4], sC[4], sV[4];
    const int wave = threadIdx.x >> 6;
    if ((threadIdx.x & 63) == 0) { sL[wave] = L; sC[wave] = C; sV[wave] = V; }
    __syncthreads();
    if (threadIdx.x == 0) {
        float l = 0.0f, c = 0.0f, v = 0.0f;
        #pragma unroll
        for (int w = 0; w < 4; ++w) { l += sL[w]; c += sC[w]; v += sV[w]; }
        out[0] = -l / v;
        out[1] = c;
        out[2] = v;
    }
}

extern "C" void kernel_launch(void* const* d_in, const int* in_sizes, int n_in,
                              void* d_out, int out_size, void* d_ws, size_t ws_size,
                              hipStream_t stream) {
    const float* out0   = (const float*)d_in[0];
    const float* out1   = (const float*)d_in[1];
    const float* out2   = (const float*)d_in[2];
    const int*   labels = (const int*)  d_in[3];
    const float* mask   = (const float*)d_in[4];
    const float* reward = (const float*)d_in[5];

    float4* partials = (float4*)d_ws;   // 2048 * 16 B = 32 KB

    shortloss_main<<<NBLOCKS, BLOCK, 0, stream>>>(
        out0, out1, out2, labels, mask, reward, partials);
    shortloss_reduce<<<1, 256, 0, stream>>>(partials, (float*)d_out);
}